// Round 3
// baseline (255.274 us; speedup 1.0000x reference)
//
#include <hip/hip_runtime.h>

// Biaffine: B=8, L=512, H=768, O=12
// inputs (B,L,H) fp32 ; weight1 (H,O,H) fp32 ; weight2 (2H+1,O) fp32 ;
// mask (B,L) int32 ; out (B,O,L,L) FLOAT32.
//
// R11: counted-vmcnt deep pipeline (T4) in the 256x256 fp8 GEMM.
// R10 measured gemm2 = 75 us, MfmaUtil 9.6%, staging BW 2.0 TB/s: 1 block/CU
// (LDS+VGPR forced) and __syncthreads' vmcnt(0) drain killed in-flight depth.
// New schedule per K-step: s_waitcnt vmcnt(8) [old tile only, never 0
// mid-loop] -> s_barrier -> ds_read+MFMA (setprio 1) -> lgkmcnt(0) ->
// s_barrier -> stage tile t+2 into the freed buffer. Prefetch depth 2,
// 8-16 loads/wave always in flight. Same epilogues; error budget unchanged.

#define NEGV 1e12f

typedef __attribute__((ext_vector_type(4))) float f32x4;
typedef __attribute__((ext_vector_type(8))) int   i32x8;

// ---- float -> OCP e4m3fn (software fallback: flush |v|<2^-6, RHU, sat 448) ----
__device__ __forceinline__ unsigned char f2fp8(float f) {
    union { float f; unsigned u; } c; c.f = f;
    unsigned s = (c.u >> 24) & 0x80;
    unsigned a = c.u & 0x7FFFFFFF;
    if (a < 0x3C800000u) return (unsigned char)s;        // |v| < 2^-6 -> 0
    a += 0x80000;                                        // round at bit 20
    int e = (int)(a >> 23) - 127;
    unsigned m = (a >> 20) & 7;
    if (e > 8 || (e == 8 && m == 7)) return (unsigned char)(s | 0x7E);  // sat 448
    return (unsigned char)(s | ((e + 7) << 3) | m);
}

// two floats -> two packed e4m3 bytes (HW cvt if available: RNE + denormals)
__device__ __forceinline__ unsigned pk_fp8x2(float a, float b) {
#if __has_builtin(__builtin_amdgcn_cvt_pk_fp8_f32)
    return (unsigned)__builtin_amdgcn_cvt_pk_fp8_f32(a, b, 0, false) & 0xFFFFu;
#else
    return (unsigned)f2fp8(a) | ((unsigned)f2fp8(b) << 8);
#endif
}

// global->LDS async copy, 16B per lane; LDS dest is wave-uniform base + lane*16
#define GLDS(gp, lp) __builtin_amdgcn_global_load_lds( \
    (__attribute__((address_space(1))) void*)(gp),     \
    (__attribute__((address_space(3))) void*)(lp), 16, 0, 0)

// ---------------- cast inputs fp32 -> fp8 ----------------
__global__ void cast_a_kernel(const float* __restrict__ in,
                              unsigned* __restrict__ out, int n4) {
    int i = blockIdx.x * blockDim.x + threadIdx.x;
    if (i < n4) {
        float4 v = ((const float4*)in)[i];
        out[i] = pk_fp8x2(v.x, v.y) | (pk_fp8x2(v.z, v.w) << 16);
    }
}

// ---- transpose weight1 (768 x 9216) -> W1T (9216 x 768) fp8, pre-scaled x16 ----
__global__ void transpose_w1_kernel(const float* __restrict__ w1,
                                    unsigned char* __restrict__ w1t) {
    __shared__ float t[64][65];
    const int n0 = blockIdx.x * 64;    // 9216/64 = 144
    const int i0 = blockIdx.y * 64;    // 768/64  = 12
    const int c  = threadIdx.x & 63;
    const int r4 = threadIdx.x >> 6;   // 0..3
    #pragma unroll
    for (int p = 0; p < 16; ++p) {
        int il = p * 4 + r4;
        t[il][c] = w1[(size_t)(i0 + il) * 9216 + n0 + c];
    }
    __syncthreads();
    #pragma unroll
    for (int p = 0; p < 16; ++p) {
        int nl = p * 4 + r4;
        w1t[(size_t)(n0 + nl) * 768 + i0 + c] =
            (unsigned char)(pk_fp8x2(t[c][nl] * 16.0f, 0.0f) & 0xFF);
    }
}

// ---------------- lin_i / lin_j (inputs @ wa, inputs @ wb), fp32 ----------------
__global__ void lin_kernel(const float* __restrict__ x, const float* __restrict__ w2,
                           float* __restrict__ li, float* __restrict__ lj) {
    int t = blockIdx.x * blockDim.x + threadIdx.x;
    if (t >= 4096 * 12) return;
    int bx = t / 12, o = t % 12;
    const float4* xp4 = (const float4*)(x + (size_t)bx * 768);
    float sa = 0.f, sb = 0.f;
    for (int h4 = 0; h4 < 192; ++h4) {
        float4 v = xp4[h4];
        int h = h4 * 4;
        sa += v.x * w2[h * 12 + o]        + v.y * w2[(h + 1) * 12 + o]
            + v.z * w2[(h + 2) * 12 + o]  + v.w * w2[(h + 3) * 12 + o];
        sb += v.x * w2[(768 + h) * 12 + o]       + v.y * w2[(769 + h) * 12 + o]
            + v.z * w2[(770 + h) * 12 + o]       + v.w * w2[(771 + h) * 12 + o];
    }
    li[t] = sa; lj[t] = sb;
}

// -------- 256x256xBK=128 fp8 bt-GEMM, depth-2 counted-vmcnt pipeline --------
// A: 256 rows, pitch lda (bytes), K-contiguous. B: 256 rows (N dim), pitch ldb.
// LDS: row r = 128 B; eight 16B slots, slot s holds global chunk s^(r&7).
// K fixed at 768 (6 tiles). Schedule per iteration t (fully unrolled):
//   s_waitcnt vmcnt(8)  [tile t complete; tile t+1's 8 loads stay in flight]
//   s_barrier           [all waves' tile-t loads visible]
//   ds_read fragments of buf[t&1] + MFMA (setprio 1)
//   s_waitcnt lgkmcnt(0); s_barrier   [all waves done reading buf[t&1]]
//   if (t<4) stage tile t+2 -> buf[t&1]   [8 GLDS/wave]
// Last iteration uses vmcnt(0). Prologue stages tiles 0,1 with no drain.
__device__ __forceinline__ void gemm256_fp8(
    const unsigned char* __restrict__ A, int lda,
    const unsigned char* __restrict__ B, int ldb,
    char* As, char* Bs, f32x4 (&acc)[8][4], int sA, int sB) {
    const int tid  = threadIdx.x;
    const int lane = tid & 63;
    const int wave = tid >> 6;
    // staging: per tile 2048 chunks of 16B each for A and B (256 rows x 8 slots)
    const unsigned char* aSrc[4]; const unsigned char* bSrc[4];
    int off[4];
    #pragma unroll
    for (int p = 0; p < 4; ++p) {
        const int cc = tid + 512 * p;
        const int row = cc >> 3, slot = cc & 7;
        const int g = slot ^ (row & 7);                 // global chunk staged here
        aSrc[p] = A + (size_t)row * lda + g * 16;
        bSrc[p] = B + (size_t)row * ldb + g * 16;
        off[p] = cc * 16;
    }
    const int wm = (wave >> 2) * 128;   // wave row-block in 256x256 tile
    const int wn = (wave & 3) * 64;     // wave col-block
    const int fr = lane & 15;           // fragment row (m or n)
    const int kg = lane >> 4;           // k-group: bytes kg*32..kg*32+31

    // prologue: stage tile 0 -> buf0, tile 1 -> buf1 (16 loads/wave in flight)
    #pragma unroll
    for (int p = 0; p < 4; ++p) GLDS(aSrc[p], As + off[p]);
    #pragma unroll
    for (int p = 0; p < 4; ++p) GLDS(bSrc[p], Bs + off[p]);
    #pragma unroll
    for (int p = 0; p < 4; ++p) GLDS(aSrc[p] + 128, As + 32768 + off[p]);
    #pragma unroll
    for (int p = 0; p < 4; ++p) GLDS(bSrc[p] + 128, Bs + 32768 + off[p]);

    #pragma unroll
    for (int t = 0; t < 6; ++t) {
        const int cur = t & 1;
        // wait ONLY for tile t's 8 loads (tile t+1's 8 remain in flight);
        // final iteration drains everything.
        if (t < 5) asm volatile("s_waitcnt vmcnt(8)" ::: "memory");
        else       asm volatile("s_waitcnt vmcnt(0)" ::: "memory");
        __builtin_amdgcn_sched_barrier(0);
        __builtin_amdgcn_s_barrier();     // all waves' tile-t data now in LDS
        const char* Ab = As + cur * 32768;
        const char* Bb = Bs + cur * 32768;
        i32x8 bf[4];
        #pragma unroll
        for (int ni = 0; ni < 4; ++ni) {
            const int r = wn + ni * 16 + fr;
            const uint4 lo = *(const uint4*)(Bb + r * 128 + ((2 * kg    ) ^ (r & 7)) * 16);
            const uint4 hi = *(const uint4*)(Bb + r * 128 + ((2 * kg + 1) ^ (r & 7)) * 16);
            bf[ni][0] = lo.x; bf[ni][1] = lo.y; bf[ni][2] = lo.z; bf[ni][3] = lo.w;
            bf[ni][4] = hi.x; bf[ni][5] = hi.y; bf[ni][6] = hi.z; bf[ni][7] = hi.w;
        }
        __builtin_amdgcn_s_setprio(1);
        #pragma unroll
        for (int mi = 0; mi < 8; ++mi) {
            const int r = wm + mi * 16 + fr;
            const uint4 lo = *(const uint4*)(Ab + r * 128 + ((2 * kg    ) ^ (r & 7)) * 16);
            const uint4 hi = *(const uint4*)(Ab + r * 128 + ((2 * kg + 1) ^ (r & 7)) * 16);
            i32x8 af;
            af[0] = lo.x; af[1] = lo.y; af[2] = lo.z; af[3] = lo.w;
            af[4] = hi.x; af[5] = hi.y; af[6] = hi.z; af[7] = hi.w;
            #pragma unroll
            for (int ni = 0; ni < 4; ++ni)
                acc[mi][ni] = __builtin_amdgcn_mfma_scale_f32_16x16x128_f8f6f4(
                    af, bf[ni], acc[mi][ni], 0, 0, 0, sA, 0, sB);
        }
        __builtin_amdgcn_s_setprio(0);
        // all my ds_reads of buf[cur] retired; after barrier, everyone's are.
        asm volatile("s_waitcnt lgkmcnt(0)" ::: "memory");
        __builtin_amdgcn_sched_barrier(0);
        __builtin_amdgcn_s_barrier();
        if (t < 4) {                      // stage tile t+2 into the freed buffer
            const int kk = (t + 2) * 128;
            #pragma unroll
            for (int p = 0; p < 4; ++p) GLDS(aSrc[p] + kk, As + cur * 32768 + off[p]);
            #pragma unroll
            for (int p = 0; p < 4; ++p) GLDS(bSrc[p] + kk, Bs + cur * 32768 + off[p]);
        }
    }
}

// ---- GEMM1: U = A(4096x768) x W1T(9216x768)^T, fp8 out pitch 9216 ----
// grid 576 = 16 m-tiles x 36 n-tiles, XCD-chunked so each XCD sweeps all of A
// (3 MB, L2-resident) over a contiguous n-band.
__global__ __launch_bounds__(512, 2) void gemm1_kernel(
    const unsigned char* __restrict__ A8,
    const unsigned char* __restrict__ W8,
    unsigned char* __restrict__ U) {
    __shared__ __align__(16) char As[2 * 32768];
    __shared__ __align__(16) char Bs[2 * 32768];
    const int orig = blockIdx.x;
    const int swz  = (orig & 7) * 72 + (orig >> 3);   // 576 = 8*72, bijective
    const int m0 = (swz & 15) * 256;
    const int n0 = (swz >> 4) * 256;
    f32x4 acc[8][4] = {};
    gemm256_fp8(A8 + (size_t)m0 * 768, 768, W8 + (size_t)n0 * 768, 768,
                As, Bs, acc, 0x7F7F7F7F, 0x7B7B7B7B);  // scaleB 2^-4 undoes x16
    const int lane = threadIdx.x & 63;
    const int wave = threadIdx.x >> 6;
    const int wm = (wave >> 2) * 128, wn = (wave & 3) * 64;
    const int rl = (lane >> 4) * 4, cl = lane & 15;
    #pragma unroll
    for (int mi = 0; mi < 8; ++mi) {
        const int m = m0 + wm + mi * 16 + rl;
        #pragma unroll
        for (int ni = 0; ni < 4; ++ni) {
            const int n = n0 + wn + ni * 16 + cl;
            const unsigned p01 = pk_fp8x2(acc[mi][ni][0], acc[mi][ni][1]);
            const unsigned p23 = pk_fp8x2(acc[mi][ni][2], acc[mi][ni][3]);
            U[(size_t)(m    ) * 9216 + n] = (unsigned char)(p01 & 0xFF);
            U[(size_t)(m + 1) * 9216 + n] = (unsigned char)(p01 >> 8);
            U[(size_t)(m + 2) * 9216 + n] = (unsigned char)(p23 & 0xFF);
            U[(size_t)(m + 3) * 9216 + n] = (unsigned char)(p23 >> 8);
        }
    }
}

// ---- GEMM2 + epilogue: out[b,o,x,y] (fp32), 384 blocks = 96 (b,o) x 2 x 2 ----
__global__ __launch_bounds__(512, 2) void gemm2_kernel(
    const unsigned char* __restrict__ U,
    const unsigned char* __restrict__ A8,
    const float* __restrict__ li,
    const float* __restrict__ lj,
    const float* __restrict__ w2,
    const int* __restrict__ mask,
    float* __restrict__ out) {
    __shared__ __align__(16) char As[2 * 32768];
    __shared__ __align__(16) char Bs[2 * 32768];
    const int orig = blockIdx.x;
    const int swz  = (orig & 7) * 48 + (orig >> 3);   // 384 = 8*48, bijective
    const int bo = swz >> 2;              // 0..95
    const int b = bo / 12, o = bo % 12;
    const int x0 = (swz & 1) * 256;
    const int y0 = ((swz >> 1) & 1) * 256;
    f32x4 acc[8][4] = {};
    gemm256_fp8(U + (size_t)(b * 512 + x0) * 9216 + (size_t)o * 768, 9216,
                A8 + (size_t)(b * 512 + y0) * 768, 768,
                As, Bs, acc, 0x7F7F7F7F, 0x7F7F7F7F);
    const float bias = w2[1536 * 12 + o];
    float* outp = out + (size_t)bo * 512 * 512;
    const int lane = threadIdx.x & 63;
    const int wave = threadIdx.x >> 6;
    const int wm = (wave >> 2) * 128, wn = (wave & 3) * 64;
    const int rl = (lane >> 4) * 4, cl = lane & 15;
    float ljv[4]; int mc[4];
    #pragma unroll
    for (int ni = 0; ni < 4; ++ni) {
        const int y = y0 + wn + ni * 16 + cl;
        ljv[ni] = lj[(size_t)(b * 512 + y) * 12 + o];
        mc[ni]  = mask[b * 512 + y];
    }
    #pragma unroll
    for (int mi = 0; mi < 8; ++mi) {
        const int xb = x0 + wm + mi * 16 + rl;
        float liv[4]; int mr[4];
        #pragma unroll
        for (int r = 0; r < 4; ++r) {
            liv[r] = li[(size_t)(b * 512 + xb + r) * 12 + o];
            mr[r]  = mask[b * 512 + xb + r];
        }
        #pragma unroll
        for (int ni = 0; ni < 4; ++ni) {
            const int y = y0 + wn + ni * 16 + cl;
            #pragma unroll
            for (int r = 0; r < 4; ++r) {
                float v = acc[mi][ni][r] + liv[r] + ljv[ni] + bias;
                if (!(mr[r] & mc[ni])) v = -NEGV;      // row or col masked -> exactly -1e12
                if (xb + r > y)        v -= NEGV;      // strict lower triangle -> extra -1e12
                outp[(size_t)(xb + r) * 512 + y] = v;   // FP32 store
            }
        }
    }
}

extern "C" void kernel_launch(void* const* d_in, const int* in_sizes, int n_in,
                              void* d_out, int out_size, void* d_ws, size_t ws_size,
                              hipStream_t stream) {
    const float* inputs = (const float*)d_in[0];
    const float* w1     = (const float*)d_in[1];
    const float* w2     = (const float*)d_in[2];
    const int*   mask   = (const int*)d_in[3];
    float* outp = (float*)d_out;

    // workspace layout (46.1 MB used)
    char* ws = (char*)d_ws;
    float* li         = (float*)(ws + 0);                  //    196,608 B
    float* lj         = (float*)(ws + 196608);             //    196,608 B
    unsigned char* A8 = (unsigned char*)(ws + 393216);     //  3,145,728 B
    unsigned char* W8 = (unsigned char*)(ws + 3538944);    //  7,077,888 B
    unsigned char* U8 = (unsigned char*)(ws + 10616832);   // 37,748,736 B -> ends 48,365,568

    cast_a_kernel<<<3072, 256, 0, stream>>>(inputs, (unsigned*)A8, 786432);
    lin_kernel<<<192, 256, 0, stream>>>(inputs, w2, li, lj);
    transpose_w1_kernel<<<dim3(144, 12), 256, 0, stream>>>(w1, W8);
    gemm1_kernel<<<576, 512, 0, stream>>>(A8, W8, U8);
    gemm2_kernel<<<384, 512, 0, stream>>>(U8, A8, li, lj, w2, mask, outp);
}

// Round 4
// 248.967 us; speedup vs baseline: 1.0253x; 1.0253x over previous
//
#include <hip/hip_runtime.h>

// Biaffine: B=8, L=512, H=768, O=12
// inputs (B,L,H) fp32 ; weight1 (H,O,H) fp32 ; weight2 (2H+1,O) fp32 ;
// mask (B,L) int32 ; out (B,O,L,L) FLOAT32.
//
// R12: differential schedules + prep fusion.
// R11 post-mortem: gemm2 75 -> <60 us (counted-vmcnt works where operands are
// HBM/L3-latency-bound) but total flat 251.7->255.3 -> suspect gemm1 regressed
// under the asm-pinned schedule (its operands are L2-resident; compiler dbuf
// was already fine -- m141/m190 pattern). So: gemm1 uses the R10 syncthreads
// dbuf (best measured for it), gemm2 keeps R11 counted-vmcnt depth-2 (best
// measured for it). cast/lin/transpose fused into one prep_kernel (saves 2
// launch gaps; jobs overlap on the CU array). Error budget unchanged.

#define NEGV 1e12f

typedef __attribute__((ext_vector_type(4))) float f32x4;
typedef __attribute__((ext_vector_type(8))) int   i32x8;

// ---- float -> OCP e4m3fn (software fallback: flush |v|<2^-6, RHU, sat 448) ----
__device__ __forceinline__ unsigned char f2fp8(float f) {
    union { float f; unsigned u; } c; c.f = f;
    unsigned s = (c.u >> 24) & 0x80;
    unsigned a = c.u & 0x7FFFFFFF;
    if (a < 0x3C800000u) return (unsigned char)s;        // |v| < 2^-6 -> 0
    a += 0x80000;                                        // round at bit 20
    int e = (int)(a >> 23) - 127;
    unsigned m = (a >> 20) & 7;
    if (e > 8 || (e == 8 && m == 7)) return (unsigned char)(s | 0x7E);  // sat 448
    return (unsigned char)(s | ((e + 7) << 3) | m);
}

// two floats -> two packed e4m3 bytes (HW cvt if available: RNE + denormals)
__device__ __forceinline__ unsigned pk_fp8x2(float a, float b) {
#if __has_builtin(__builtin_amdgcn_cvt_pk_fp8_f32)
    return (unsigned)__builtin_amdgcn_cvt_pk_fp8_f32(a, b, 0, false) & 0xFFFFu;
#else
    return (unsigned)f2fp8(a) | ((unsigned)f2fp8(b) << 8);
#endif
}

// global->LDS async copy, 16B per lane; LDS dest is wave-uniform base + lane*16
#define GLDS(gp, lp) __builtin_amdgcn_global_load_lds( \
    (__attribute__((address_space(1))) void*)(gp),     \
    (__attribute__((address_space(3))) void*)(lp), 16, 0, 0)

// ---------------- fused prep: cast A -> fp8 | lin_i/lin_j | transpose W1 ----------------
// blocks [0,3072): cast 786432 float4s; [3072,3264): lin (49152 rows*o);
// [3264,4992): 64x64 transpose tiles of weight1 -> W1T fp8 (pre-scaled x16).
__global__ __launch_bounds__(256) void prep_kernel(
    const float* __restrict__ in, const float* __restrict__ w1,
    const float* __restrict__ w2, unsigned* __restrict__ A8,
    unsigned char* __restrict__ W8, float* __restrict__ li,
    float* __restrict__ lj) {
    __shared__ float t[64][65];
    const int bx = blockIdx.x;
    if (bx < 3072) {                       // ---- cast inputs fp32 -> fp8 ----
        const int i = bx * 256 + threadIdx.x;   // < 786432 always
        float4 v = ((const float4*)in)[i];
        A8[i] = pk_fp8x2(v.x, v.y) | (pk_fp8x2(v.z, v.w) << 16);
    } else if (bx < 3264) {                // ---- lin_i / lin_j ----
        const int tt = (bx - 3072) * 256 + threadIdx.x;   // < 49152 = 4096*12
        const int r = tt / 12, o = tt % 12;
        const float4* xp4 = (const float4*)(in + (size_t)r * 768);
        float sa = 0.f, sb = 0.f;
        for (int h4 = 0; h4 < 192; ++h4) {
            float4 v = xp4[h4];
            int h = h4 * 4;
            sa += v.x * w2[h * 12 + o]       + v.y * w2[(h + 1) * 12 + o]
                + v.z * w2[(h + 2) * 12 + o] + v.w * w2[(h + 3) * 12 + o];
            sb += v.x * w2[(768 + h) * 12 + o] + v.y * w2[(769 + h) * 12 + o]
                + v.z * w2[(770 + h) * 12 + o] + v.w * w2[(771 + h) * 12 + o];
        }
        li[tt] = sa; lj[tt] = sb;
    } else {                               // ---- transpose weight1 -> fp8 x16 ----
        const int b2 = bx - 3264;          // 0..1727
        const int n0 = (b2 % 144) * 64;    // 9216/64 = 144
        const int i0 = (b2 / 144) * 64;    // 768/64  = 12
        const int c  = threadIdx.x & 63;
        const int r4 = threadIdx.x >> 6;   // 0..3
        #pragma unroll
        for (int p = 0; p < 16; ++p) {
            int il = p * 4 + r4;
            t[il][c] = w1[(size_t)(i0 + il) * 9216 + n0 + c];
        }
        __syncthreads();
        #pragma unroll
        for (int p = 0; p < 16; ++p) {
            int nl = p * 4 + r4;
            W8[(size_t)(n0 + nl) * 768 + i0 + c] =
                (unsigned char)(pk_fp8x2(t[c][nl] * 16.0f, 0.0f) & 0xFF);
        }
    }
}

// -------- 256x256xBK=128 fp8 bt-GEMM core, schedule-templated --------
// A: 256 rows, pitch lda (bytes), K-contiguous. B: 256 rows (N dim), pitch ldb.
// LDS: row r = 128 B; eight 16B slots, slot s holds global chunk s^(r&7).
// K fixed at 768 (6 tiles).
// COUNTED=false: R10 schedule -- depth-1 dbuf, prefetch before compute, one
//   __syncthreads (vmcnt(0) drain) per step. Best for L2-resident operands.
// COUNTED=true: R11 schedule -- depth-2, s_waitcnt vmcnt(8) (never 0
//   mid-loop), setprio around MFMA, restage after lgkmcnt(0)+barrier. Best
//   for long-latency (L3/HBM first-touch) operands.
template <bool COUNTED>
__device__ __forceinline__ void gemm256_fp8(
    const unsigned char* __restrict__ A, int lda,
    const unsigned char* __restrict__ B, int ldb,
    char* As, char* Bs, f32x4 (&acc)[8][4], int sA, int sB) {
    const int tid  = threadIdx.x;
    const int lane = tid & 63;
    const int wave = tid >> 6;
    const unsigned char* aSrc[4]; const unsigned char* bSrc[4];
    int off[4];
    #pragma unroll
    for (int p = 0; p < 4; ++p) {
        const int cc = tid + 512 * p;
        const int row = cc >> 3, slot = cc & 7;
        const int g = slot ^ (row & 7);                 // global chunk staged here
        aSrc[p] = A + (size_t)row * lda + g * 16;
        bSrc[p] = B + (size_t)row * ldb + g * 16;
        off[p] = cc * 16;
    }
    const int wm = (wave >> 2) * 128;   // wave row-block in 256x256 tile
    const int wn = (wave & 3) * 64;     // wave col-block
    const int fr = lane & 15;           // fragment row (m or n)
    const int kg = lane >> 4;           // k-group: bytes kg*32..kg*32+31

    if (!COUNTED) {
        // ---- R10 schedule: depth-1 dbuf + __syncthreads ----
        #pragma unroll
        for (int p = 0; p < 4; ++p) GLDS(aSrc[p], As + off[p]);
        #pragma unroll
        for (int p = 0; p < 4; ++p) GLDS(bSrc[p], Bs + off[p]);
        __syncthreads();
        int cur = 0;
        for (int t = 1; t <= 6; ++t) {
            const int nxt = cur ^ 1;
            if (t < 6) {                     // issue next-tile prefetch FIRST
                const int kk = t * 128;
                #pragma unroll
                for (int p = 0; p < 4; ++p) GLDS(aSrc[p] + kk, As + nxt * 32768 + off[p]);
                #pragma unroll
                for (int p = 0; p < 4; ++p) GLDS(bSrc[p] + kk, Bs + nxt * 32768 + off[p]);
            }
            const char* Ab = As + cur * 32768;
            const char* Bb = Bs + cur * 32768;
            i32x8 bf[4];
            #pragma unroll
            for (int ni = 0; ni < 4; ++ni) {
                const int r = wn + ni * 16 + fr;
                const uint4 lo = *(const uint4*)(Bb + r * 128 + ((2 * kg    ) ^ (r & 7)) * 16);
                const uint4 hi = *(const uint4*)(Bb + r * 128 + ((2 * kg + 1) ^ (r & 7)) * 16);
                bf[ni][0] = lo.x; bf[ni][1] = lo.y; bf[ni][2] = lo.z; bf[ni][3] = lo.w;
                bf[ni][4] = hi.x; bf[ni][5] = hi.y; bf[ni][6] = hi.z; bf[ni][7] = hi.w;
            }
            #pragma unroll
            for (int mi = 0; mi < 8; ++mi) {
                const int r = wm + mi * 16 + fr;
                const uint4 lo = *(const uint4*)(Ab + r * 128 + ((2 * kg    ) ^ (r & 7)) * 16);
                const uint4 hi = *(const uint4*)(Ab + r * 128 + ((2 * kg + 1) ^ (r & 7)) * 16);
                i32x8 af;
                af[0] = lo.x; af[1] = lo.y; af[2] = lo.z; af[3] = lo.w;
                af[4] = hi.x; af[5] = hi.y; af[6] = hi.z; af[7] = hi.w;
                #pragma unroll
                for (int ni = 0; ni < 4; ++ni)
                    acc[mi][ni] = __builtin_amdgcn_mfma_scale_f32_16x16x128_f8f6f4(
                        af, bf[ni], acc[mi][ni], 0, 0, 0, sA, 0, sB);
            }
            __syncthreads();                 // drains prefetch + fences LDS
            cur = nxt;
        }
        return;
    }

    // ---- R11 schedule: depth-2, counted vmcnt ----
    #pragma unroll
    for (int p = 0; p < 4; ++p) GLDS(aSrc[p], As + off[p]);
    #pragma unroll
    for (int p = 0; p < 4; ++p) GLDS(bSrc[p], Bs + off[p]);
    #pragma unroll
    for (int p = 0; p < 4; ++p) GLDS(aSrc[p] + 128, As + 32768 + off[p]);
    #pragma unroll
    for (int p = 0; p < 4; ++p) GLDS(bSrc[p] + 128, Bs + 32768 + off[p]);

    #pragma unroll
    for (int t = 0; t < 6; ++t) {
        const int cur = t & 1;
        if (t < 5) asm volatile("s_waitcnt vmcnt(8)" ::: "memory");
        else       asm volatile("s_waitcnt vmcnt(0)" ::: "memory");
        __builtin_amdgcn_sched_barrier(0);
        __builtin_amdgcn_s_barrier();     // all waves' tile-t data now in LDS
        const char* Ab = As + cur * 32768;
        const char* Bb = Bs + cur * 32768;
        i32x8 bf[4];
        #pragma unroll
        for (int ni = 0; ni < 4; ++ni) {
            const int r = wn + ni * 16 + fr;
            const uint4 lo = *(const uint4*)(Bb + r * 128 + ((2 * kg    ) ^ (r & 7)) * 16);
            const uint4 hi = *(const uint4*)(Bb + r * 128 + ((2 * kg + 1) ^ (r & 7)) * 16);
            bf[ni][0] = lo.x; bf[ni][1] = lo.y; bf[ni][2] = lo.z; bf[ni][3] = lo.w;
            bf[ni][4] = hi.x; bf[ni][5] = hi.y; bf[ni][6] = hi.z; bf[ni][7] = hi.w;
        }
        __builtin_amdgcn_s_setprio(1);
        #pragma unroll
        for (int mi = 0; mi < 8; ++mi) {
            const int r = wm + mi * 16 + fr;
            const uint4 lo = *(const uint4*)(Ab + r * 128 + ((2 * kg    ) ^ (r & 7)) * 16);
            const uint4 hi = *(const uint4*)(Ab + r * 128 + ((2 * kg + 1) ^ (r & 7)) * 16);
            i32x8 af;
            af[0] = lo.x; af[1] = lo.y; af[2] = lo.z; af[3] = lo.w;
            af[4] = hi.x; af[5] = hi.y; af[6] = hi.z; af[7] = hi.w;
            #pragma unroll
            for (int ni = 0; ni < 4; ++ni)
                acc[mi][ni] = __builtin_amdgcn_mfma_scale_f32_16x16x128_f8f6f4(
                    af, bf[ni], acc[mi][ni], 0, 0, 0, sA, 0, sB);
        }
        __builtin_amdgcn_s_setprio(0);
        asm volatile("s_waitcnt lgkmcnt(0)" ::: "memory");
        __builtin_amdgcn_sched_barrier(0);
        __builtin_amdgcn_s_barrier();     // everyone done reading buf[cur]
        if (t < 4) {                      // stage tile t+2 into the freed buffer
            const int kk = (t + 2) * 128;
            #pragma unroll
            for (int p = 0; p < 4; ++p) GLDS(aSrc[p] + kk, As + cur * 32768 + off[p]);
            #pragma unroll
            for (int p = 0; p < 4; ++p) GLDS(bSrc[p] + kk, Bs + cur * 32768 + off[p]);
        }
    }
}

// ---- GEMM1: U = A(4096x768) x W1T(9216x768)^T, fp8 out pitch 9216 ----
// grid 576 = 16 m-tiles x 36 n-tiles, XCD-chunked so each XCD sweeps all of A
// (3 MB, L2-resident) over a contiguous n-band. R10 schedule (L2-resident).
__global__ __launch_bounds__(512, 2) void gemm1_kernel(
    const unsigned char* __restrict__ A8,
    const unsigned char* __restrict__ W8,
    unsigned char* __restrict__ U) {
    __shared__ __align__(16) char As[2 * 32768];
    __shared__ __align__(16) char Bs[2 * 32768];
    const int orig = blockIdx.x;
    const int swz  = (orig & 7) * 72 + (orig >> 3);   // 576 = 8*72, bijective
    const int m0 = (swz & 15) * 256;
    const int n0 = (swz >> 4) * 256;
    f32x4 acc[8][4] = {};
    gemm256_fp8<false>(A8 + (size_t)m0 * 768, 768, W8 + (size_t)n0 * 768, 768,
                       As, Bs, acc, 0x7F7F7F7F, 0x7B7B7B7B);  // scaleB 2^-4 undoes x16
    const int lane = threadIdx.x & 63;
    const int wave = threadIdx.x >> 6;
    const int wm = (wave >> 2) * 128, wn = (wave & 3) * 64;
    const int rl = (lane >> 4) * 4, cl = lane & 15;
    #pragma unroll
    for (int mi = 0; mi < 8; ++mi) {
        const int m = m0 + wm + mi * 16 + rl;
        #pragma unroll
        for (int ni = 0; ni < 4; ++ni) {
            const int n = n0 + wn + ni * 16 + cl;
            const unsigned p01 = pk_fp8x2(acc[mi][ni][0], acc[mi][ni][1]);
            const unsigned p23 = pk_fp8x2(acc[mi][ni][2], acc[mi][ni][3]);
            U[(size_t)(m    ) * 9216 + n] = (unsigned char)(p01 & 0xFF);
            U[(size_t)(m + 1) * 9216 + n] = (unsigned char)(p01 >> 8);
            U[(size_t)(m + 2) * 9216 + n] = (unsigned char)(p23 & 0xFF);
            U[(size_t)(m + 3) * 9216 + n] = (unsigned char)(p23 >> 8);
        }
    }
}

// ---- GEMM2 + epilogue: out[b,o,x,y] (fp32), 384 blocks = 96 (b,o) x 2 x 2 ----
// R11 counted schedule (U is L3/HBM first-touch -> long latency).
__global__ __launch_bounds__(512, 2) void gemm2_kernel(
    const unsigned char* __restrict__ U,
    const unsigned char* __restrict__ A8,
    const float* __restrict__ li,
    const float* __restrict__ lj,
    const float* __restrict__ w2,
    const int* __restrict__ mask,
    float* __restrict__ out) {
    __shared__ __align__(16) char As[2 * 32768];
    __shared__ __align__(16) char Bs[2 * 32768];
    const int orig = blockIdx.x;
    const int swz  = (orig & 7) * 48 + (orig >> 3);   // 384 = 8*48, bijective
    const int bo = swz >> 2;              // 0..95
    const int b = bo / 12, o = bo % 12;
    const int x0 = (swz & 1) * 256;
    const int y0 = ((swz >> 1) & 1) * 256;
    f32x4 acc[8][4] = {};
    gemm256_fp8<true>(U + (size_t)(b * 512 + x0) * 9216 + (size_t)o * 768, 9216,
                      A8 + (size_t)(b * 512 + y0) * 768, 768,
                      As, Bs, acc, 0x7F7F7F7F, 0x7F7F7F7F);
    const float bias = w2[1536 * 12 + o];
    float* outp = out + (size_t)bo * 512 * 512;
    const int lane = threadIdx.x & 63;
    const int wave = threadIdx.x >> 6;
    const int wm = (wave >> 2) * 128, wn = (wave & 3) * 64;
    const int rl = (lane >> 4) * 4, cl = lane & 15;
    float ljv[4]; int mc[4];
    #pragma unroll
    for (int ni = 0; ni < 4; ++ni) {
        const int y = y0 + wn + ni * 16 + cl;
        ljv[ni] = lj[(size_t)(b * 512 + y) * 12 + o];
        mc[ni]  = mask[b * 512 + y];
    }
    #pragma unroll
    for (int mi = 0; mi < 8; ++mi) {
        const int xb = x0 + wm + mi * 16 + rl;
        float liv[4]; int mr[4];
        #pragma unroll
        for (int r = 0; r < 4; ++r) {
            liv[r] = li[(size_t)(b * 512 + xb + r) * 12 + o];
            mr[r]  = mask[b * 512 + xb + r];
        }
        #pragma unroll
        for (int ni = 0; ni < 4; ++ni) {
            const int y = y0 + wn + ni * 16 + cl;
            #pragma unroll
            for (int r = 0; r < 4; ++r) {
                float v = acc[mi][ni][r] + liv[r] + ljv[ni] + bias;
                if (!(mr[r] & mc[ni])) v = -NEGV;      // row or col masked -> exactly -1e12
                if (xb + r > y)        v -= NEGV;      // strict lower triangle -> extra -1e12
                outp[(size_t)(xb + r) * 512 + y] = v;   // FP32 store
            }
        }
    }
}

extern "C" void kernel_launch(void* const* d_in, const int* in_sizes, int n_in,
                              void* d_out, int out_size, void* d_ws, size_t ws_size,
                              hipStream_t stream) {
    const float* inputs = (const float*)d_in[0];
    const float* w1     = (const float*)d_in[1];
    const float* w2     = (const float*)d_in[2];
    const int*   mask   = (const int*)d_in[3];
    float* outp = (float*)d_out;

    // workspace layout (46.1 MB used)
    char* ws = (char*)d_ws;
    float* li         = (float*)(ws + 0);                  //    196,608 B
    float* lj         = (float*)(ws + 196608);             //    196,608 B
    unsigned char* A8 = (unsigned char*)(ws + 393216);     //  3,145,728 B
    unsigned char* W8 = (unsigned char*)(ws + 3538944);    //  7,077,888 B
    unsigned char* U8 = (unsigned char*)(ws + 10616832);   // 37,748,736 B -> ends 48,365,568

    prep_kernel<<<4992, 256, 0, stream>>>(inputs, w1, w2, (unsigned*)A8, W8, li, lj);
    gemm1_kernel<<<576, 512, 0, stream>>>(A8, W8, U8);
    gemm2_kernel<<<384, 512, 0, stream>>>(U8, A8, li, lj, w2, mask, outp);
}

// Round 5
// 211.436 us; speedup vs baseline: 1.2073x; 1.1775x over previous
//
#include <hip/hip_runtime.h>

// Biaffine: B=8, L=512, H=768, O=12
// inputs (B,L,H) fp32 ; weight1 (H,O,H) fp32 ; weight2 (2H+1,O) fp32 ;
// mask (B,L) int32 ; out (B,O,L,L) FLOAT32.
//
// R13: kill the hidden lin tail. R12 profile: prep = 83-111 us even with all
// inputs L3-warm (hbm_bytes 10 MB, VALUBusy 3%) -> pure latency tail from the
// lin section (192 blocks < 256 CUs, 192-iter serial reduce, 12x-redundant
// 16B gathers). Fix: lin IS a GEMM -- fold it into gemm1 as 24 extra N
// columns (W1T extended to 9472 rows: wa^T*16, wb^T*16, zero pad; same
// scaleB=2^-4 path). li/lj come back out of U as fp8 (0.7-scale values, ~6%
// rel err -> ~0.05 additive logit error vs 4.5 budget). gemm1 grid 576->592.
// prep = cast + float4/dword-vectorized transpose + 256 tiny ext-row blocks.
// gemm1 keeps R10 syncthreads dbuf; gemm2 keeps R11 counted-vmcnt depth-2.

#define NEGV 1e12f

typedef __attribute__((ext_vector_type(4))) float f32x4;
typedef __attribute__((ext_vector_type(8))) int   i32x8;

// ---- float -> OCP e4m3fn (software fallback: flush |v|<2^-6, RHU, sat 448) ----
__device__ __forceinline__ unsigned char f2fp8(float f) {
    union { float f; unsigned u; } c; c.f = f;
    unsigned s = (c.u >> 24) & 0x80;
    unsigned a = c.u & 0x7FFFFFFF;
    if (a < 0x3C800000u) return (unsigned char)s;        // |v| < 2^-6 -> 0
    a += 0x80000;                                        // round at bit 20
    int e = (int)(a >> 23) - 127;
    unsigned m = (a >> 20) & 7;
    if (e > 8 || (e == 8 && m == 7)) return (unsigned char)(s | 0x7E);  // sat 448
    return (unsigned char)(s | ((e + 7) << 3) | m);
}

// two floats -> two packed e4m3 bytes (HW cvt if available: RNE + denormals)
__device__ __forceinline__ unsigned pk_fp8x2(float a, float b) {
#if __has_builtin(__builtin_amdgcn_cvt_pk_fp8_f32)
    return (unsigned)__builtin_amdgcn_cvt_pk_fp8_f32(a, b, 0, false) & 0xFFFFu;
#else
    return (unsigned)f2fp8(a) | ((unsigned)f2fp8(b) << 8);
#endif
}

// e4m3fn byte -> float (HW cvt if available)
__device__ __forceinline__ float fp8_to_f32(unsigned char b) {
#if __has_builtin(__builtin_amdgcn_cvt_f32_fp8)
    return __builtin_amdgcn_cvt_f32_fp8((int)b, 0);
#else
    const int s = b >> 7, e = (b >> 3) & 15, m = b & 7;
    float mag = e ? __builtin_ldexpf((float)(8 + m), e - 10)
                  : __builtin_ldexpf((float)m, -9);
    return s ? -mag : mag;
#endif
}

// global->LDS async copy, 16B per lane; LDS dest is wave-uniform base + lane*16
#define GLDS(gp, lp) __builtin_amdgcn_global_load_lds( \
    (__attribute__((address_space(1))) void*)(gp),     \
    (__attribute__((address_space(3))) void*)(lp), 16, 0, 0)

// ------- fused prep: cast A -> fp8 | transpose W1 -> fp8 x16 | W ext rows -------
// blocks [0,3072): cast 786432 float4s of inputs.
// blocks [3072,4800): 64x64 transpose tiles of weight1 (768x9216) -> W8 rows.
// blocks [4800,5056): W8 extension rows 9216..9471 (wa^T*16, wb^T*16, zeros).
__global__ __launch_bounds__(256) void prep_kernel(
    const float* __restrict__ in, const float* __restrict__ w1,
    const float* __restrict__ w2, unsigned* __restrict__ A8,
    unsigned char* __restrict__ W8) {
    __shared__ float t[64][68];        // pad 4 floats: float4-aligned, bank-spread
    const int bx  = blockIdx.x;
    const int tid = threadIdx.x;
    if (bx < 3072) {                       // ---- cast inputs fp32 -> fp8 ----
        const int i = bx * 256 + tid;      // < 786432 always
        float4 v = ((const float4*)in)[i];
        A8[i] = pk_fp8x2(v.x, v.y) | (pk_fp8x2(v.z, v.w) << 16);
    } else if (bx < 4800) {                // ---- transpose weight1 -> fp8 x16 ----
        const int b2 = bx - 3072;          // 0..1727
        const int n0 = (b2 % 144) * 64;    // 9216/64 = 144
        const int i0 = (b2 / 144) * 64;    // 768/64  = 12
        const int g  = tid >> 4;           // 0..15
        const int q  = tid & 15;           // 0..15
        #pragma unroll
        for (int p = 0; p < 4; ++p) {      // load 16 rows x 64 cols per phase
            const int il = p * 16 + g;
            float4 v = *(const float4*)(w1 + (size_t)(i0 + il) * 9216 + n0 + q * 4);
            *(float4*)&t[il][q * 4] = v;
        }
        __syncthreads();
        #pragma unroll
        for (int p = 0; p < 4; ++p) {      // store 16 out-rows x 64 bytes per phase
            const int nl = p * 16 + g;
            const int iq = q * 4;
            const unsigned lo = pk_fp8x2(t[iq    ][nl] * 16.0f, t[iq + 1][nl] * 16.0f);
            const unsigned hi = pk_fp8x2(t[iq + 2][nl] * 16.0f, t[iq + 3][nl] * 16.0f);
            *(unsigned*)(W8 + (size_t)(n0 + nl) * 768 + i0 + iq) = lo | (hi << 16);
        }
    } else {                               // ---- extension rows 9216..9471 ----
        const int j = bx - 4800;           // 0..255 -> W8 row 9216+j
        unsigned char* dst = W8 + (size_t)(9216 + j) * 768;
        if (j < 24) {                      // wa (j<12) / wb (j>=12) column, x16
            #pragma unroll
            for (int k = 0; k < 3; ++k) {
                const int h = tid * 3 + k;
                const int col = (j < 12) ? (h * 12 + j) : ((768 + h) * 12 + (j - 12));
                dst[h] = (unsigned char)(pk_fp8x2(w2[col] * 16.0f, 0.0f) & 0xFF);
            }
        } else {                           // zero pad rows
            if (tid < 192) ((unsigned*)dst)[tid] = 0u;
        }
    }
}

// -------- 256x256xBK=128 fp8 bt-GEMM core, schedule-templated --------
// A: 256 rows, pitch lda (bytes), K-contiguous. B: 256 rows (N dim), pitch ldb.
// LDS: row r = 128 B; eight 16B slots, slot s holds global chunk s^(r&7).
// K fixed at 768 (6 tiles).
// COUNTED=false: R10 schedule -- depth-1 dbuf, prefetch before compute, one
//   __syncthreads (vmcnt(0) drain) per step. Best for L2-resident operands.
// COUNTED=true: R11 schedule -- depth-2, s_waitcnt vmcnt(8) (never 0
//   mid-loop), setprio around MFMA, restage after lgkmcnt(0)+barrier. Best
//   for long-latency (L3/HBM first-touch) operands.
template <bool COUNTED>
__device__ __forceinline__ void gemm256_fp8(
    const unsigned char* __restrict__ A, int lda,
    const unsigned char* __restrict__ B, int ldb,
    char* As, char* Bs, f32x4 (&acc)[8][4], int sA, int sB) {
    const int tid  = threadIdx.x;
    const int lane = tid & 63;
    const int wave = tid >> 6;
    const unsigned char* aSrc[4]; const unsigned char* bSrc[4];
    int off[4];
    #pragma unroll
    for (int p = 0; p < 4; ++p) {
        const int cc = tid + 512 * p;
        const int row = cc >> 3, slot = cc & 7;
        const int g = slot ^ (row & 7);                 // global chunk staged here
        aSrc[p] = A + (size_t)row * lda + g * 16;
        bSrc[p] = B + (size_t)row * ldb + g * 16;
        off[p] = cc * 16;
    }
    const int wm = (wave >> 2) * 128;   // wave row-block in 256x256 tile
    const int wn = (wave & 3) * 64;     // wave col-block
    const int fr = lane & 15;           // fragment row (m or n)
    const int kg = lane >> 4;           // k-group: bytes kg*32..kg*32+31

    if (!COUNTED) {
        // ---- R10 schedule: depth-1 dbuf + __syncthreads ----
        #pragma unroll
        for (int p = 0; p < 4; ++p) GLDS(aSrc[p], As + off[p]);
        #pragma unroll
        for (int p = 0; p < 4; ++p) GLDS(bSrc[p], Bs + off[p]);
        __syncthreads();
        int cur = 0;
        for (int t = 1; t <= 6; ++t) {
            const int nxt = cur ^ 1;
            if (t < 6) {                     // issue next-tile prefetch FIRST
                const int kk = t * 128;
                #pragma unroll
                for (int p = 0; p < 4; ++p) GLDS(aSrc[p] + kk, As + nxt * 32768 + off[p]);
                #pragma unroll
                for (int p = 0; p < 4; ++p) GLDS(bSrc[p] + kk, Bs + nxt * 32768 + off[p]);
            }
            const char* Ab = As + cur * 32768;
            const char* Bb = Bs + cur * 32768;
            i32x8 bf[4];
            #pragma unroll
            for (int ni = 0; ni < 4; ++ni) {
                const int r = wn + ni * 16 + fr;
                const uint4 lo = *(const uint4*)(Bb + r * 128 + ((2 * kg    ) ^ (r & 7)) * 16);
                const uint4 hi = *(const uint4*)(Bb + r * 128 + ((2 * kg + 1) ^ (r & 7)) * 16);
                bf[ni][0] = lo.x; bf[ni][1] = lo.y; bf[ni][2] = lo.z; bf[ni][3] = lo.w;
                bf[ni][4] = hi.x; bf[ni][5] = hi.y; bf[ni][6] = hi.z; bf[ni][7] = hi.w;
            }
            #pragma unroll
            for (int mi = 0; mi < 8; ++mi) {
                const int r = wm + mi * 16 + fr;
                const uint4 lo = *(const uint4*)(Ab + r * 128 + ((2 * kg    ) ^ (r & 7)) * 16);
                const uint4 hi = *(const uint4*)(Ab + r * 128 + ((2 * kg + 1) ^ (r & 7)) * 16);
                i32x8 af;
                af[0] = lo.x; af[1] = lo.y; af[2] = lo.z; af[3] = lo.w;
                af[4] = hi.x; af[5] = hi.y; af[6] = hi.z; af[7] = hi.w;
                #pragma unroll
                for (int ni = 0; ni < 4; ++ni)
                    acc[mi][ni] = __builtin_amdgcn_mfma_scale_f32_16x16x128_f8f6f4(
                        af, bf[ni], acc[mi][ni], 0, 0, 0, sA, 0, sB);
            }
            __syncthreads();                 // drains prefetch + fences LDS
            cur = nxt;
        }
        return;
    }

    // ---- R11 schedule: depth-2, counted vmcnt ----
    #pragma unroll
    for (int p = 0; p < 4; ++p) GLDS(aSrc[p], As + off[p]);
    #pragma unroll
    for (int p = 0; p < 4; ++p) GLDS(bSrc[p], Bs + off[p]);
    #pragma unroll
    for (int p = 0; p < 4; ++p) GLDS(aSrc[p] + 128, As + 32768 + off[p]);
    #pragma unroll
    for (int p = 0; p < 4; ++p) GLDS(bSrc[p] + 128, Bs + 32768 + off[p]);

    #pragma unroll
    for (int t = 0; t < 6; ++t) {
        const int cur = t & 1;
        if (t < 5) asm volatile("s_waitcnt vmcnt(8)" ::: "memory");
        else       asm volatile("s_waitcnt vmcnt(0)" ::: "memory");
        __builtin_amdgcn_sched_barrier(0);
        __builtin_amdgcn_s_barrier();     // all waves' tile-t data now in LDS
        const char* Ab = As + cur * 32768;
        const char* Bb = Bs + cur * 32768;
        i32x8 bf[4];
        #pragma unroll
        for (int ni = 0; ni < 4; ++ni) {
            const int r = wn + ni * 16 + fr;
            const uint4 lo = *(const uint4*)(Bb + r * 128 + ((2 * kg    ) ^ (r & 7)) * 16);
            const uint4 hi = *(const uint4*)(Bb + r * 128 + ((2 * kg + 1) ^ (r & 7)) * 16);
            bf[ni][0] = lo.x; bf[ni][1] = lo.y; bf[ni][2] = lo.z; bf[ni][3] = lo.w;
            bf[ni][4] = hi.x; bf[ni][5] = hi.y; bf[ni][6] = hi.z; bf[ni][7] = hi.w;
        }
        __builtin_amdgcn_s_setprio(1);
        #pragma unroll
        for (int mi = 0; mi < 8; ++mi) {
            const int r = wm + mi * 16 + fr;
            const uint4 lo = *(const uint4*)(Ab + r * 128 + ((2 * kg    ) ^ (r & 7)) * 16);
            const uint4 hi = *(const uint4*)(Ab + r * 128 + ((2 * kg + 1) ^ (r & 7)) * 16);
            i32x8 af;
            af[0] = lo.x; af[1] = lo.y; af[2] = lo.z; af[3] = lo.w;
            af[4] = hi.x; af[5] = hi.y; af[6] = hi.z; af[7] = hi.w;
            #pragma unroll
            for (int ni = 0; ni < 4; ++ni)
                acc[mi][ni] = __builtin_amdgcn_mfma_scale_f32_16x16x128_f8f6f4(
                    af, bf[ni], acc[mi][ni], 0, 0, 0, sA, 0, sB);
        }
        __builtin_amdgcn_s_setprio(0);
        asm volatile("s_waitcnt lgkmcnt(0)" ::: "memory");
        __builtin_amdgcn_sched_barrier(0);
        __builtin_amdgcn_s_barrier();     // everyone done reading buf[cur]
        if (t < 4) {                      // stage tile t+2 into the freed buffer
            const int kk = (t + 2) * 128;
            #pragma unroll
            for (int p = 0; p < 4; ++p) GLDS(aSrc[p] + kk, As + cur * 32768 + off[p]);
            #pragma unroll
            for (int p = 0; p < 4; ++p) GLDS(bSrc[p] + kk, Bs + cur * 32768 + off[p]);
        }
    }
}

// ---- GEMM1: U = A(4096x768) x W8(9472x768)^T, fp8 out pitch 9472 ----
// Columns 9216..9239 of U are li (o=0..11) and lj (o=0..11); 9240.. are zero.
// grid 592 = 16 m-tiles x 37 n-tiles, XCD-chunked (592 = 8*74, bijective).
__global__ __launch_bounds__(512, 2) void gemm1_kernel(
    const unsigned char* __restrict__ A8,
    const unsigned char* __restrict__ W8,
    unsigned char* __restrict__ U) {
    __shared__ __align__(16) char As[2 * 32768];
    __shared__ __align__(16) char Bs[2 * 32768];
    const int orig = blockIdx.x;
    const int swz  = (orig & 7) * 74 + (orig >> 3);   // 592 = 8*74, bijective
    const int m0 = (swz & 15) * 256;
    const int n0 = (swz >> 4) * 256;
    f32x4 acc[8][4] = {};
    gemm256_fp8<false>(A8 + (size_t)m0 * 768, 768, W8 + (size_t)n0 * 768, 768,
                       As, Bs, acc, 0x7F7F7F7F, 0x7B7B7B7B);  // scaleB 2^-4 undoes x16
    const int lane = threadIdx.x & 63;
    const int wave = threadIdx.x >> 6;
    const int wm = (wave >> 2) * 128, wn = (wave & 3) * 64;
    const int rl = (lane >> 4) * 4, cl = lane & 15;
    #pragma unroll
    for (int mi = 0; mi < 8; ++mi) {
        const int m = m0 + wm + mi * 16 + rl;
        #pragma unroll
        for (int ni = 0; ni < 4; ++ni) {
            const int n = n0 + wn + ni * 16 + cl;
            const unsigned p01 = pk_fp8x2(acc[mi][ni][0], acc[mi][ni][1]);
            const unsigned p23 = pk_fp8x2(acc[mi][ni][2], acc[mi][ni][3]);
            U[(size_t)(m    ) * 9472 + n] = (unsigned char)(p01 & 0xFF);
            U[(size_t)(m + 1) * 9472 + n] = (unsigned char)(p01 >> 8);
            U[(size_t)(m + 2) * 9472 + n] = (unsigned char)(p23 & 0xFF);
            U[(size_t)(m + 3) * 9472 + n] = (unsigned char)(p23 >> 8);
        }
    }
}

// ---- GEMM2 + epilogue: out[b,o,x,y] (fp32), 384 blocks = 96 (b,o) x 2 x 2 ----
// R11 counted schedule (U is L3/HBM first-touch -> long latency).
// li/lj decoded from U's fp8 extension columns (9216+o / 9228+o).
__global__ __launch_bounds__(512, 2) void gemm2_kernel(
    const unsigned char* __restrict__ U,
    const unsigned char* __restrict__ A8,
    const float* __restrict__ w2,
    const int* __restrict__ mask,
    float* __restrict__ out) {
    __shared__ __align__(16) char As[2 * 32768];
    __shared__ __align__(16) char Bs[2 * 32768];
    const int orig = blockIdx.x;
    const int swz  = (orig & 7) * 48 + (orig >> 3);   // 384 = 8*48, bijective
    const int bo = swz >> 2;              // 0..95
    const int b = bo / 12, o = bo % 12;
    const int x0 = (swz & 1) * 256;
    const int y0 = ((swz >> 1) & 1) * 256;
    f32x4 acc[8][4] = {};
    gemm256_fp8<true>(U + (size_t)(b * 512 + x0) * 9472 + (size_t)o * 768, 9472,
                      A8 + (size_t)(b * 512 + y0) * 768, 768,
                      As, Bs, acc, 0x7F7F7F7F, 0x7F7F7F7F);
    const float bias = w2[1536 * 12 + o];
    float* outp = out + (size_t)bo * 512 * 512;
    const int lane = threadIdx.x & 63;
    const int wave = threadIdx.x >> 6;
    const int wm = (wave >> 2) * 128, wn = (wave & 3) * 64;
    const int rl = (lane >> 4) * 4, cl = lane & 15;
    float ljv[4]; int mc[4];
    #pragma unroll
    for (int ni = 0; ni < 4; ++ni) {
        const int y = y0 + wn + ni * 16 + cl;
        ljv[ni] = fp8_to_f32(U[(size_t)(b * 512 + y) * 9472 + 9228 + o]);
        mc[ni]  = mask[b * 512 + y];
    }
    #pragma unroll
    for (int mi = 0; mi < 8; ++mi) {
        const int xb = x0 + wm + mi * 16 + rl;
        float liv[4]; int mr[4];
        #pragma unroll
        for (int r = 0; r < 4; ++r) {
            liv[r] = fp8_to_f32(U[(size_t)(b * 512 + xb + r) * 9472 + 9216 + o]);
            mr[r]  = mask[b * 512 + xb + r];
        }
        #pragma unroll
        for (int ni = 0; ni < 4; ++ni) {
            const int y = y0 + wn + ni * 16 + cl;
            #pragma unroll
            for (int r = 0; r < 4; ++r) {
                float v = acc[mi][ni][r] + liv[r] + ljv[ni] + bias;
                if (!(mr[r] & mc[ni])) v = -NEGV;      // row or col masked -> exactly -1e12
                if (xb + r > y)        v -= NEGV;      // strict lower triangle -> extra -1e12
                outp[(size_t)(xb + r) * 512 + y] = v;   // FP32 store
            }
        }
    }
}

extern "C" void kernel_launch(void* const* d_in, const int* in_sizes, int n_in,
                              void* d_out, int out_size, void* d_ws, size_t ws_size,
                              hipStream_t stream) {
    const float* inputs = (const float*)d_in[0];
    const float* w1     = (const float*)d_in[1];
    const float* w2     = (const float*)d_in[2];
    const int*   mask   = (const int*)d_in[3];
    float* outp = (float*)d_out;

    // workspace layout (49.2 MB used)
    char* ws = (char*)d_ws;
    unsigned char* A8 = (unsigned char*)(ws + 0);          //  3,145,728 B
    unsigned char* W8 = (unsigned char*)(ws + 3145728);    //  7,274,496 B (9472 x 768)
    unsigned char* U8 = (unsigned char*)(ws + 10420224);   // 38,797,312 B (4096 x 9472)

    prep_kernel<<<5056, 256, 0, stream>>>(inputs, w1, w2, (unsigned*)A8, W8);
    gemm1_kernel<<<592, 512, 0, stream>>>(A8, W8, U8);
    gemm2_kernel<<<384, 512, 0, stream>>>(U8, A8, w2, mask, outp);
}